// Round 5
// baseline (42.790 us; speedup 1.0000x reference)
//
#include <hip/hip_runtime.h>
#include <hip/hip_bf16.h>

// ---------------------------------------------------------------------------
// PointNet2 FP module, 2 launches:
//   prep_w:   W1 -> W1t[256][448] bf16 (zero-pad K>=387), W2 -> W2t[256][256]
//   fp_fused2: per block (64 skip rows, 512 thr = 8 waves, 2 waves/SIMD):
//     phase1: knn(k=3)+interp+concat -> H-tile in LDS (4-point ILP per wave)
//     phase2: GEMM1 (K=448, BK=64) from LDS-H, W1 staged 2-buffer counted-vmcnt
//     phase3: h1 (bias+relu, bf16) -> LDS (aliases dead H)
//     phase4: GEMM2 (K=256) from LDS-h1, W2 staged -> out fp32
// ---------------------------------------------------------------------------

typedef __bf16 bf16x8 __attribute__((ext_vector_type(8)));
typedef float  f32x4  __attribute__((ext_vector_type(4)));

__device__ __forceinline__ unsigned short f2bf(float f) {
  __hip_bfloat16 h = __float2bfloat16(f);
  return __builtin_bit_cast(unsigned short, h);
}

#define GLDS16(G, L)                                                          \
  __builtin_amdgcn_global_load_lds(                                           \
      (const __attribute__((address_space(1))) void*)(G),                     \
      (__attribute__((address_space(3))) void*)(L), 16, 0, 0)

#define BAR()    __builtin_amdgcn_s_barrier()
#define WAITV(N) asm volatile("s_waitcnt vmcnt(" #N ")" ::: "memory")
#define WAITL()  asm volatile("s_waitcnt lgkmcnt(0)" ::: "memory")

static constexpr int MROWS = 16384;
static constexpr int KP1   = 448;   // 7 * 64
static constexpr int KREAL = 387;
static constexpr int NK1   = 7;     // 448 / 64
static constexpr int NK2   = 4;     // 256 / 64
static constexpr int HSTR  = 456;   // H LDS row stride (shorts)
static constexpr int H1STR = 264;   // h1 LDS row stride (shorts)

// ---------------- prep: W1t[256][448], W2t[256][256] bf16 (LDS transpose) ---
__global__ __launch_bounds__(256) void prep_w(
    const float* __restrict__ W1, const float* __restrict__ W2,
    unsigned short* __restrict__ W1t, unsigned short* __restrict__ W2t)
{
  __shared__ float T[64][65];
  int b = blockIdx.x;
  const float* S; unsigned short* D; int KP, Kreal, kb, nb;
  if (b < 28) { S = W1; D = W1t; KP = KP1; Kreal = KREAL; kb = b >> 2; nb = b & 3; }
  else { b -= 28; S = W2; D = W2t; KP = 256; Kreal = 256; kb = b >> 2; nb = b & 3; }
  const int k0 = kb << 6, n0 = nb << 6;
  const int tr = threadIdx.x >> 4, tc = threadIdx.x & 15;
#pragma unroll
  for (int i = 0; i < 4; ++i) {
    const int k = k0 + i * 16 + tr;
    float4 v = make_float4(0.f, 0.f, 0.f, 0.f);
    if (k < Kreal) v = *(const float4*)(S + (size_t)k * 256 + n0 + tc * 4);
    T[i * 16 + tr][tc * 4 + 0] = v.x;
    T[i * 16 + tr][tc * 4 + 1] = v.y;
    T[i * 16 + tr][tc * 4 + 2] = v.z;
    T[i * 16 + tr][tc * 4 + 3] = v.w;
  }
  __syncthreads();
#pragma unroll
  for (int i = 0; i < 4; ++i) {
    const int n = n0 + i * 16 + tr;
    const int k = k0 + tc * 4;
    ushort4 o;
    o.x = f2bf(T[tc * 4 + 0][i * 16 + tr]);
    o.y = f2bf(T[tc * 4 + 1][i * 16 + tr]);
    o.z = f2bf(T[tc * 4 + 2][i * 16 + tr]);
    o.w = f2bf(T[tc * 4 + 3][i * 16 + tr]);
    *(ushort4*)(D + (size_t)n * KP + k) = o;
  }
}

// ---------------------------- the fused kernel ------------------------------
__global__ __launch_bounds__(512, 2) void fp_fused2(
    const float* __restrict__ in_x,      // [4096, 256]
    const float* __restrict__ in_pos,    // [4096, 3]
    const float* __restrict__ skip_x,    // [16384, 128]
    const float* __restrict__ skip_pos,  // [16384, 3]
    const unsigned short* __restrict__ W1t,  // [256][448] bf16
    const unsigned short* __restrict__ W2t,  // [256][256] bf16
    const float* __restrict__ bias1, const float* __restrict__ bias2,
    float* __restrict__ out)             // [16384, 256]
{
  __shared__ unsigned short HU[64 * HSTR];     // 58,368 B; h1 aliases this
  __shared__ unsigned short Bs[2][256 * 64];   // 65,536 B (W K-chunks)
  __shared__ float Ps[768];                    //  3,072 B

  const int tid = threadIdx.x, lane = tid & 63, wid = tid >> 6;
  const int m0 = blockIdx.x << 6;          // first skip row
  const int ib = (m0 >> 10) << 8;          // first in-point of batch
  const int fr = lane & 15, g = lane >> 4;
  const int rg = wid >> 2, cg = wid & 3;   // wave tile: 32 rows x 64 cols

// W-chunk stage: [256 rows][64 k] bf16, XOR-involution chunk swizzle.
// 4 GLDS16 per thread (vmcnt 4 per stage). LDS dest linear.
#define STAGEW(Wp, KW, ks, buf)                                               \
  {                                                                           \
    _Pragma("unroll")                                                         \
    for (int r_ = 0; r_ < 4; ++r_) {                                          \
      const int f_   = r_ * 512 + tid;                                        \
      const int row_ = f_ >> 3;                                               \
      const int c_   = (f_ & 7) ^ (row_ & 7);                                 \
      GLDS16(Wp + (size_t)row_ * (KW) + (ks) * 64 + c_ * 8,                   \
             &Bs[buf][(r_ * 512 + wid * 64) * 8]);                            \
    }                                                                         \
  }

  // stage batch in_pos SoA, then issue GEMM1 prologue W-stages (hide under knn)
  for (int i = tid; i < 768; i += 512)
    Ps[(i % 3) * 256 + i / 3] = in_pos[(size_t)ib * 3 + i];
  STAGEW(W1t, KP1, 0, 0);
  STAGEW(W1t, KP1, 1, 1);
  WAITL(); BAR();

  // ---- phase 1: knn(k=3)+interp+concat, 8 pts/wave, 4-point ILP ----
  float Pxr[4], Pyr[4], Pzr[4];
#pragma unroll
  for (int q = 0; q < 4; ++q) {
    Pxr[q] = Ps[lane + q * 64];
    Pyr[q] = Ps[256 + lane + q * 64];
    Pzr[q] = Ps[512 + lane + q * 64];
  }
  float spv = 0.f;
  if (lane < 24) spv = skip_pos[(size_t)(m0 + wid * 8) * 3 + lane];

#pragma unroll 1
  for (int grp = 0; grp < 2; ++grp) {
    float sx[4], sy[4], sz[4], d2[4][4];
#pragma unroll
    for (int u = 0; u < 4; ++u) {
      const int pt = grp * 4 + u;
      sx[u] = __shfl(spv, 3 * pt + 0);
      sy[u] = __shfl(spv, 3 * pt + 1);
      sz[u] = __shfl(spv, 3 * pt + 2);
#pragma unroll
      for (int q = 0; q < 4; ++q) {   // numpy op-order, no fma contraction
        const float dx = __fsub_rn(sx[u], Pxr[q]);
        const float dy = __fsub_rn(sy[u], Pyr[q]);
        const float dz = __fsub_rn(sz[u], Pzr[q]);
        d2[u][q] = __fadd_rn(__fadd_rn(__fmul_rn(dx, dx), __fmul_rn(dy, dy)),
                             __fmul_rn(dz, dz));
      }
    }
    int gsel[4][3]; float wsel[4][3], wsum[4] = {0.f, 0.f, 0.f, 0.f};
#pragma unroll
    for (int p = 0; p < 3; ++p) {
      float bd[4]; int bi[4];
#pragma unroll
      for (int u = 0; u < 4; ++u) {
        bd[u] = d2[u][0]; bi[u] = lane;
#pragma unroll
        for (int q = 1; q < 4; ++q)
          if (d2[u][q] < bd[u]) { bd[u] = d2[u][q]; bi[u] = lane + (q << 6); }
      }
#pragma unroll
      for (int mk = 1; mk < 64; mk <<= 1) {   // 4 interleaved argmin butterflies
#pragma unroll
        for (int u = 0; u < 4; ++u) {
          const float od = __shfl_xor(bd[u], mk);
          const int   oi = __shfl_xor(bi[u], mk);
          if (od < bd[u] || (od == bd[u] && oi < bi[u])) { bd[u] = od; bi[u] = oi; }
        }
      }
#pragma unroll
      for (int u = 0; u < 4; ++u) {
        const bool win = ((bi[u] & 63) == lane);
        const int  qw  = bi[u] >> 6;          // static-index removal
        d2[u][0] = (win && qw == 0) ? 3.4e38f : d2[u][0];
        d2[u][1] = (win && qw == 1) ? 3.4e38f : d2[u][1];
        d2[u][2] = (win && qw == 2) ? 3.4e38f : d2[u][2];
        d2[u][3] = (win && qw == 3) ? 3.4e38f : d2[u][3];
        gsel[u][p] = bi[u];
        const float w = 1.0f / fmaxf(sqrtf(bd[u]), 1e-10f);
        wsel[u][p] = w; wsum[u] += w;
      }
    }
#pragma unroll
    for (int u = 0; u < 4; ++u) {
      const int lr = wid * 8 + grp * 4 + u;   // local row 0..63
      const int s  = m0 + lr;
      const float denom = wsum[u] + 1e-16f;
      const float w0 = wsel[u][0] / denom;
      const float w1 = wsel[u][1] / denom;
      const float w2 = wsel[u][2] / denom;
      const f32x4 a = *(const f32x4*)(in_x + (size_t)(ib + gsel[u][0]) * 256 + lane * 4);
      const f32x4 b = *(const f32x4*)(in_x + (size_t)(ib + gsel[u][1]) * 256 + lane * 4);
      const f32x4 c = *(const f32x4*)(in_x + (size_t)(ib + gsel[u][2]) * 256 + lane * 4);
      unsigned short* hr = &HU[lr * HSTR];
      ushort4 o4;
      o4.x = f2bf(w0 * a.x + w1 * b.x + w2 * c.x);
      o4.y = f2bf(w0 * a.y + w1 * b.y + w2 * c.y);
      o4.z = f2bf(w0 * a.z + w1 * b.z + w2 * c.z);
      o4.w = f2bf(w0 * a.w + w1 * b.w + w2 * c.w);
      *(ushort4*)(hr + lane * 4) = o4;
      const float2 sv = *(const float2*)(skip_x + (size_t)s * 128 + lane * 2);
      ushort2 o2; o2.x = f2bf(sv.x); o2.y = f2bf(sv.y);
      *(ushort2*)(hr + 256 + lane * 2) = o2;
      // cols 384..447: pos(3) + zero pad (all 64 lanes)
      const float v = (lane == 0) ? sx[u] : (lane == 1) ? sy[u]
                    : (lane == 2) ? sz[u] : 0.f;
      hr[384 + lane] = f2bf(v);
    }
  }
  WAITL(); BAR();   // H-tile ready

  // ---- GEMM setup: fragment offsets ----
  int Rwbase[4], Rw7[4], Rh[2];
#pragma unroll
  for (int i = 0; i < 4; ++i) {
    const int R = cg * 64 + i * 16 + fr;   // W row = output col
    Rwbase[i] = R * 64;
    Rw7[i]    = R & 7;
  }
#pragma unroll
  for (int i = 0; i < 2; ++i) Rh[i] = rg * 32 + i * 16 + fr;   // output row

  f32x4 bv1[4], bv2[4];
#pragma unroll
  for (int mc = 0; mc < 4; ++mc) {
    bv1[mc] = *(const f32x4*)(bias1 + cg * 64 + mc * 16 + g * 4);
    bv2[mc] = *(const f32x4*)(bias2 + cg * 64 + mc * 16 + g * 4);
  }

  f32x4 acc[4][2] = {};   // [mc = col frag][rf = row frag]

  // ---- phase 2: GEMM1, 7 K-steps of 64 ----
#pragma unroll 1
  for (int ks = 0; ks < NK1; ++ks) {
    if (ks < NK1 - 1) { WAITV(4); } else { WAITV(0); }
    BAR();
    const unsigned short* bs = Bs[ks & 1];
    bf16x8 wf[4][2], hf[2][2];
#pragma unroll
    for (int kk = 0; kk < 2; ++kk) {
#pragma unroll
      for (int i = 0; i < 4; ++i)
        wf[i][kk] = *(const bf16x8*)&bs[Rwbase[i] + (((kk * 4 + g) ^ Rw7[i]) << 3)];
#pragma unroll
      for (int i = 0; i < 2; ++i)
        hf[i][kk] = *(const bf16x8*)&HU[Rh[i] * HSTR + ks * 64 + kk * 32 + g * 8];
    }
#pragma unroll
    for (int kk = 0; kk < 2; ++kk)
#pragma unroll
      for (int mc = 0; mc < 4; ++mc)
#pragma unroll
        for (int rf = 0; rf < 2; ++rf)
          acc[mc][rf] = __builtin_amdgcn_mfma_f32_16x16x32_bf16(
              wf[mc][kk], hf[rf][kk], acc[mc][rf], 0, 0, 0);
    WAITL(); BAR();
    if (ks + 2 < NK1) STAGEW(W1t, KP1, ks + 2, ks & 1);
  }

  // GEMM2 prologue staging (latency hides under h1 epilogue)
  STAGEW(W2t, 256, 0, 0);
  STAGEW(W2t, 256, 1, 1);

  // ---- phase 3: h1 = relu(acc + b1) -> LDS (aliases dead H) ----
  unsigned short* h1s = HU;
#pragma unroll
  for (int rf = 0; rf < 2; ++rf)
#pragma unroll
    for (int mc = 0; mc < 4; ++mc) {
      ushort4 o;
      o.x = f2bf(fmaxf(acc[mc][rf][0] + bv1[mc][0], 0.f));
      o.y = f2bf(fmaxf(acc[mc][rf][1] + bv1[mc][1], 0.f));
      o.z = f2bf(fmaxf(acc[mc][rf][2] + bv1[mc][2], 0.f));
      o.w = f2bf(fmaxf(acc[mc][rf][3] + bv1[mc][3], 0.f));
      *(ushort4*)&h1s[(rg * 32 + rf * 16 + fr) * H1STR + cg * 64 + mc * 16 + g * 4] = o;
    }
  WAITL(); BAR();   // h1 visible

#pragma unroll
  for (int mc = 0; mc < 4; ++mc)
#pragma unroll
    for (int rf = 0; rf < 2; ++rf) acc[mc][rf] = f32x4{0.f, 0.f, 0.f, 0.f};

  // ---- phase 4: GEMM2, 4 K-steps of 64 ----
#pragma unroll 1
  for (int ks = 0; ks < NK2; ++ks) {
    if (ks < NK2 - 1) { WAITV(4); } else { WAITV(0); }
    BAR();
    const unsigned short* bs = Bs[ks & 1];
    bf16x8 wf[4][2], hf[2][2];
#pragma unroll
    for (int kk = 0; kk < 2; ++kk) {
#pragma unroll
      for (int i = 0; i < 4; ++i)
        wf[i][kk] = *(const bf16x8*)&bs[Rwbase[i] + (((kk * 4 + g) ^ Rw7[i]) << 3)];
#pragma unroll
      for (int i = 0; i < 2; ++i)
        hf[i][kk] = *(const bf16x8*)&h1s[Rh[i] * H1STR + ks * 64 + kk * 32 + g * 8];
    }
#pragma unroll
    for (int kk = 0; kk < 2; ++kk)
#pragma unroll
      for (int mc = 0; mc < 4; ++mc)
#pragma unroll
        for (int rf = 0; rf < 2; ++rf)
          acc[mc][rf] = __builtin_amdgcn_mfma_f32_16x16x32_bf16(
              wf[mc][kk], hf[rf][kk], acc[mc][rf], 0, 0, 0);
    WAITL(); BAR();
    if (ks + 2 < NK2) STAGEW(W2t, 256, ks + 2, ks & 1);
  }
#undef STAGEW

  // ---- final epilogue: coalesced float4 stores ----
#pragma unroll
  for (int rf = 0; rf < 2; ++rf) {
    const size_t row = (size_t)(m0 + rg * 32 + rf * 16 + fr);
#pragma unroll
    for (int mc = 0; mc < 4; ++mc) {
      f32x4 o;
#pragma unroll
      for (int j = 0; j < 4; ++j) o[j] = fmaxf(acc[mc][rf][j] + bv2[mc][j], 0.f);
      *(f32x4*)(out + row * 256 + cg * 64 + mc * 16 + g * 4) = o;
    }
  }
}

// ---------------------------------------------------------------------------
extern "C" void kernel_launch(void* const* d_in, const int* in_sizes, int n_in,
                              void* d_out, int out_size, void* d_ws, size_t ws_size,
                              hipStream_t stream) {
  const float* in_x     = (const float*)d_in[0];
  const float* in_pos   = (const float*)d_in[1];
  const float* skip_x   = (const float*)d_in[3];
  const float* skip_pos = (const float*)d_in[4];
  const float* W1       = (const float*)d_in[6];
  const float* bias1    = (const float*)d_in[7];
  const float* W2       = (const float*)d_in[8];
  const float* bias2    = (const float*)d_in[9];

  char* ws = (char*)d_ws;
  unsigned short* W1t = (unsigned short*)(ws);             // 256*448*2 = 229,376
  unsigned short* W2t = (unsigned short*)(ws + 229376);    // 256*256*2 = 131,072

  prep_w<<<dim3(44), dim3(256), 0, stream>>>(W1, W2, W1t, W2t);
  fp_fused2<<<dim3(MROWS / 64), dim3(512), 0, stream>>>(
      in_x, in_pos, skip_x, skip_pos, W1t, W2t, bias1, bias2, (float*)d_out);
}